// Round 15
// baseline (110.763 us; speedup 1.0000x reference)
//
#include <hip/hip_runtime.h>

typedef __bf16 bf16;
typedef __bf16 bf16x4 __attribute__((ext_vector_type(4)));
typedef __bf16 bf16x8 __attribute__((ext_vector_type(8)));
typedef float f32x2 __attribute__((ext_vector_type(2)));
typedef float f32x4 __attribute__((ext_vector_type(4)));
typedef float f32x16 __attribute__((ext_vector_type(16)));

__device__ __forceinline__ f32x4 mfma16(bf16x8 a, bf16x8 b, f32x4 c) {
  return __builtin_amdgcn_mfma_f32_16x16x32_bf16(a, b, c, 0, 0, 0);
}
__device__ __forceinline__ f32x16 mfma32(bf16x8 a, bf16x8 b, f32x16 c) {
  return __builtin_amdgcn_mfma_f32_32x32x16_bf16(a, b, c, 0, 0, 0);
}

__device__ __forceinline__ unsigned pack2(float lo, float hi) {
  unsigned short a = __builtin_bit_cast(unsigned short, (bf16)lo);
  unsigned short b = __builtin_bit_cast(unsigned short, (bf16)hi);
  return ((unsigned)b << 16) | (unsigned)a;
}

// single-instruction packed f32->2xbf16 (T12 recipe; no builtin exists)
__device__ __forceinline__ unsigned cvtpk(float lo, float hi) {
  unsigned r;
  asm("v_cvt_pk_bf16_f32 %0, %1, %2" : "=v"(r) : "v"(lo), "v"(hi));
  return r;
}

// v_permlane32_swap_b32 a, b:  a' = {a.lo, b.lo}, b' = {a.hi, b.hi}
__device__ __forceinline__ void plane32swap(unsigned& a, unsigned& b) {
  asm volatile("v_permlane32_swap_b32 %0, %1" : "+v"(a), "+v"(b));
}

// packed f32 add: 2 floats per instruction (CDNA VOP3P)
__device__ __forceinline__ f32x2 pk_add(f32x2 a, f32x2 b) {
  f32x2 d;
  asm("v_pk_add_f32 %0, %1, %2" : "=v"(d) : "v"(a), "v"(b));
  return d;
}

typedef __attribute__((address_space(3))) unsigned int lds_u32;
typedef __attribute__((address_space(1))) unsigned int glb_u32;
// async global->LDS, 16B per lane; LDS dest = base + lane*16 (wave-linear)
__device__ __forceinline__ void gld16(const bf16* g, bf16* l) {
  __builtin_amdgcn_global_load_lds((const glb_u32*)g, (lds_u32*)l, 16, 0, 0);
}

// ---------------------------------------------------------------------------
// prep: fused weight transposes (blocks 0..1023) + RMSNorm (blocks 1024..5119)
// ---------------------------------------------------------------------------
__global__ __launch_bounds__(256)
void prep_kernel(const float* __restrict__ t, const float* __restrict__ f,
                 const float* __restrict__ nw,
                 const float* __restrict__ wq, const float* __restrict__ wkv,
                 const float* __restrict__ wp,
                 bf16* __restrict__ tn, bf16* __restrict__ fn,
                 bf16* __restrict__ wqT, bf16* __restrict__ wkvT,
                 bf16* __restrict__ wpT)
{
  int b = blockIdx.x;
  if (b < 1024) {
    int e = b * 256 + threadIdx.x;   // 0..262143
    const float* src; bf16* dst; int N; int idx;
    if (e < 65536)       { src = wq;  dst = wqT;  N = 256; idx = e; }
    else if (e < 196608) { src = wkv; dst = wkvT; N = 512; idx = e - 65536; }
    else                 { src = wp;  dst = wpT;  N = 256; idx = e - 196608; }
    int k = idx & 255;
    int n = idx >> 8;
    dst[idx] = (bf16)src[(size_t)k * N + n];
    return;
  }
  int wave = threadIdx.x >> 6;
  int lane = threadIdx.x & 63;
  int row = (b - 1024) * 4 + wave;           // 0..16383
  const float* src;
  bf16* dst;
  if (row < 8192) {
    src = t + (size_t)row * 256;
    dst = tn + (size_t)row * 256;
  } else {
    int r2 = row - 8192;
    src = f + (size_t)r2 * 256;
    dst = fn + (size_t)r2 * 256;
  }
  float4 v = reinterpret_cast<const float4*>(src)[lane];
  float ss = v.x * v.x + v.y * v.y + v.z * v.z + v.w * v.w;
  #pragma unroll
  for (int m = 1; m < 64; m <<= 1) ss += __shfl_xor(ss, m);
  float nrm = rsqrtf(ss * (1.0f / 256.0f) + 1e-5f);
  float4 wv = reinterpret_cast<const float4*>(nw)[lane];
  bf16x4 o;
  o[0] = (bf16)(v.x * nrm * wv.x);
  o[1] = (bf16)(v.y * nrm * wv.y);
  o[2] = (bf16)(v.z * nrm * wv.z);
  o[3] = (bf16)(v.w * nrm * wv.w);
  *reinterpret_cast<bf16x4*>(dst + lane * 4) = o;
}

// ---------------------------------------------------------------------------
// LDS-staged GEMM body: out[M=8192, N] = A[8192,256](bf16) @ W[256,N] + bias
// ---------------------------------------------------------------------------
template<int MODE>
__device__ __forceinline__
void gemm_body(int bid, bf16 (*As)[264], bf16 (*Bs)[264],
               const bf16* __restrict__ A, const bf16* __restrict__ Wt,
               const float* __restrict__ bias, bf16* __restrict__ o0,
               bf16* __restrict__ o1, const bf16* __restrict__ resid,
               float* __restrict__ outf, int N)
{
  int tid = threadIdx.x;
  int wv = tid >> 6;
  int lane = tid & 63;
  int lr = lane & 15;
  int lk = (lane >> 4) * 8;
  int wm = wv >> 1, wn = wv & 1;
  int nb = N >> 6;
  int bm = bid / nb;
  int bn = bid - bm * nb;
  int row0 = bm * 64;
  int col0 = bn * 64;

  #pragma unroll
  for (int j = 0; j < 8; j++) {
    int idx = tid + 256 * j;            // 0..2047
    int r = idx >> 5, ch = idx & 31;    // row, 16B chunk
    *reinterpret_cast<bf16x8*>(&As[r][ch * 8]) =
        *reinterpret_cast<const bf16x8*>(A + (size_t)(row0 + r) * 256 + ch * 8);
    *reinterpret_cast<bf16x8*>(&Bs[r][ch * 8]) =
        *reinterpret_cast<const bf16x8*>(Wt + (size_t)(col0 + r) * 256 + ch * 8);
  }
  __syncthreads();

  f32x4 acc[2][2] = {};
  #pragma unroll
  for (int k0 = 0; k0 < 256; k0 += 32) {
    bf16x8 a[2], b[2];
    #pragma unroll
    for (int mi = 0; mi < 2; mi++)
      a[mi] = *reinterpret_cast<const bf16x8*>(&As[wm * 32 + mi * 16 + lr][k0 + lk]);
    #pragma unroll
    for (int ni = 0; ni < 2; ni++)
      b[ni] = *reinterpret_cast<const bf16x8*>(&Bs[wn * 32 + ni * 16 + lr][k0 + lk]);
    #pragma unroll
    for (int mi = 0; mi < 2; mi++)
      #pragma unroll
      for (int ni = 0; ni < 2; ni++)
        acc[mi][ni] = mfma16(a[mi], b[ni], acc[mi][ni]);
  }

  int rb = (lane >> 4) * 4;
  int row0w = row0 + wm * 32;
  int col0w = col0 + wn * 32;
  #pragma unroll
  for (int mi = 0; mi < 2; mi++) {
    #pragma unroll
    for (int ni = 0; ni < 2; ni++) {
      int col = col0w + ni * 16 + lr;
      float bv = bias[col];
      #pragma unroll
      for (int r = 0; r < 4; r++) {
        int row = row0w + mi * 16 + rb + r;
        float val = acc[mi][ni][r] + bv;
        if (MODE == 0) {
          int b_ = row >> 12, tt = row & 4095;
          int h = col >> 6, d = col & 63;
          o0[(((size_t)(b_ * 4 + h)) * 4096 + tt) * 64 + d] = (bf16)val;
        } else if (MODE == 1) {
          int b_ = row >> 12, ff = row & 4095;
          if (col < 256) {
            int h = col >> 6, d = col & 63;
            o0[(((size_t)(b_ * 4 + h)) * 4096 + ff) * 64 + d] = (bf16)val;
          } else {
            int c = col - 256;
            int h = c >> 6, d = c & 63;
            o1[(((size_t)(b_ * 4 + h)) * 64 + d) * 4096 + ff] = (bf16)val;
          }
        } else {
          size_t idx = (size_t)row * 256 + col;
          outf[idx] = val + (float)resid[idx];
        }
      }
    }
  }
}

// Fused Q-proj + KV-proj: blocks [0,512) do Q, [512,1536) do KV.
__global__ __launch_bounds__(256)
void gemm_qkv(const bf16* __restrict__ tn, const bf16* __restrict__ fn,
              const bf16* __restrict__ wqT, const bf16* __restrict__ wkvT,
              const float* __restrict__ bq, const float* __restrict__ bkv,
              bf16* __restrict__ q, bf16* __restrict__ k, bf16* __restrict__ vt)
{
  __shared__ bf16 As[64][264];
  __shared__ bf16 Bs[64][264];
  if (blockIdx.x < 512)
    gemm_body<0>(blockIdx.x, As, Bs, tn, wqT, bq, q, nullptr, nullptr, nullptr, 256);
  else
    gemm_body<1>(blockIdx.x - 512, As, Bs, fn, wkvT, bkv, k, vt, nullptr, nullptr, 512);
}

// Output projection + bias + residual.
__global__ __launch_bounds__(256)
void gemm_out(const bf16* __restrict__ ao, const bf16* __restrict__ wpT,
              const float* __restrict__ bp, const bf16* __restrict__ resid,
              float* __restrict__ outf)
{
  __shared__ bf16 As[64][264];
  __shared__ bf16 Bs[64][264];
  gemm_body<2>(blockIdx.x, As, Bs, ao, wpT, bp, nullptr, nullptr, resid, outf, 256);
}

// ---------------------------------------------------------------------------
// Flash attention v12: 2 q-tiles per wave (amortize staging/softmax overhead
// over 2x MFMA work; K/V LDS frags feed both tiles). 2-wave blocks:
// wave0 stages K (4 gld16), wave1 stages V (4 gld16); counted vmcnt(4),
// raw-barrier double-buffer; R13 staging layout verbatim.
// grid = 2048: bh = bid&7 (XCD), qb = (bid>>3)&31 (128 q rows/block),
// FQ = bid>>8 (f-eighth, 512 f, 16 iters). launch_bounds(128,3): VGPR cap
// ~170 — expected use ~150, NO spill (R2/R8 lesson: watch WRITE_SIZE).
// Fixed-M softmax (bounded scores); cvt_pk bf16 pack; pure-sum partials.
// ---------------------------------------------------------------------------
__global__ __launch_bounds__(128, 3)
void attn_kernel(const bf16* __restrict__ Q, const bf16* __restrict__ K,
                 const bf16* __restrict__ Vt, unsigned* __restrict__ Opart,
                 float* __restrict__ Lp)
{
  int bid = blockIdx.x;
  int bh = bid & 7;
  int qb = (bid >> 3) & 31;
  int FQ = bid >> 8;               // 0..7
  int wv = threadIdx.x >> 6;       // 0..1 (staging role)
  int lane = threadIdx.x & 63;
  int lq = lane & 31;
  int h32 = lane >> 5;

  const bf16* Qw = Q + ((size_t)bh * 4096 + qb * 128 + wv * 64) * 64;
  const bf16* Kb = K + (size_t)bh * 4096 * 64;
  const bf16* Vb = Vt + (size_t)bh * 64 * 4096;

  __shared__ bf16 stage[2][4096];  // [buf][ K' 2048 | V' 2048 ]  16 KB

  const float qs = 0.125f * 1.44269504089f;
  bf16x8 qfA[4], qfB[4];
  #pragma unroll
  for (int kc = 0; kc < 4; kc++) {
    qfA[kc] = *reinterpret_cast<const bf16x8*>(Qw + (size_t)lq * 64 + kc * 16 + h32 * 8);
    qfB[kc] = *reinterpret_cast<const bf16x8*>(Qw + (size_t)(32 + lq) * 64 + kc * 16 + h32 * 8);
    #pragma unroll
    for (int i = 0; i < 8; i++) {
      qfA[kc][i] = (bf16)((float)qfA[kc][i] * qs);
      qfB[kc][i] = (bf16)((float)qfB[kc][i] * qs);
    }
  }

  f32x16 zmm = {};                 // loop-invariant zero seed
  f32x16 oaA[2] = {}, oaB[2] = {};
  float lA = 0.f, lB = 0.f;

  int fbeg = FQ * 512;

  // wave0: K' chunks 0..3 (dch-major); wave1: V' chunks 0..3 (fch-major)
  const bf16 *p0, *p1;
  if (wv == 0) {
    p0 = Kb + (size_t)(fbeg + lq) * 64 + h32 * 8;
    p1 = p0 + 32 * 64;
  } else {
    p0 = Vb + (size_t)lane * 4096 + fbeg;
    p1 = p0 + 32;
  }
  const int adv = (wv == 0) ? 64 * 64 : 64;    // 2-tile source stride

  // loop-invariant per-lane LDS read bases
  const bf16* kL0 = &stage[0][0] + h32 * 256 + lq * 8;
  const bf16* kL1 = &stage[1][0] + h32 * 256 + lq * 8;
  const bf16* vL0 = &stage[0][2048] + h32 * 512 + lq * 8;
  const bf16* vL1 = &stage[1][2048] + h32 * 512 + lq * 8;

  auto STAGE = [&](bf16* sb, const bf16* p) {
    if (wv == 0) {
      gld16(p,      sb);
      gld16(p + 16, sb + 512);
      gld16(p + 32, sb + 1024);
      gld16(p + 48, sb + 1536);
    } else {
      gld16(p,      sb + 2048);
      gld16(p + 8,  sb + 2560);
      gld16(p + 16, sb + 3072);
      gld16(p + 24, sb + 3584);
    }
  };

  // one q-tile's work for one staged 32-f tile
  auto TILE = [&](const bf16* kL, const bf16* vL, const bf16x8* qf,
                  f32x16* oa, float& l) {
    f32x16 st = mfma32(*reinterpret_cast<const bf16x8*>(kL),        qf[0], zmm);
    st        = mfma32(*reinterpret_cast<const bf16x8*>(kL + 512),  qf[1], st);
    st        = mfma32(*reinterpret_cast<const bf16x8*>(kL + 1024), qf[2], st);
    st        = mfma32(*reinterpret_cast<const bf16x8*>(kL + 1536), qf[3], st);

    // fixed-M: p = exp2(st)
    union { f32x16 v; f32x2 p2[8]; float s[16]; } u;
    #pragma unroll
    for (int r = 0; r < 16; r++) u.s[r] = exp2f(st[r]);

    // per-half l sum (lane halves combined at epilogue)
    f32x2 a0 = pk_add(u.p2[0], u.p2[1]);
    f32x2 a1 = pk_add(u.p2[2], u.p2[3]);
    f32x2 a2 = pk_add(u.p2[4], u.p2[5]);
    f32x2 a3 = pk_add(u.p2[6], u.p2[7]);
    a0 = pk_add(a0, a1);
    a2 = pk_add(a2, a3);
    a0 = pk_add(a0, a2);
    l += a0[0] + a0[1];

    // P^T -> B-fragments: cvt_pk then permlane32_swap pairs
    unsigned w[8];
    #pragma unroll
    for (int j = 0; j < 8; j++) w[j] = cvtpk(u.s[2 * j], u.s[2 * j + 1]);
    plane32swap(w[0], w[2]);
    plane32swap(w[1], w[3]);
    plane32swap(w[4], w[6]);
    plane32swap(w[5], w[7]);
    union { unsigned u4[4]; bf16x8 v; } ub0, ub1;
    ub0.u4[0] = w[0]; ub0.u4[1] = w[1]; ub0.u4[2] = w[2]; ub0.u4[3] = w[3];
    ub1.u4[0] = w[4]; ub1.u4[1] = w[5]; ub1.u4[2] = w[6]; ub1.u4[3] = w[7];

    oa[0] = mfma32(*reinterpret_cast<const bf16x8*>(vL),        ub0.v, oa[0]);
    oa[0] = mfma32(*reinterpret_cast<const bf16x8*>(vL + 1024), ub1.v, oa[0]);
    oa[1] = mfma32(*reinterpret_cast<const bf16x8*>(vL + 256),  ub0.v, oa[1]);
    oa[1] = mfma32(*reinterpret_cast<const bf16x8*>(vL + 1280), ub1.v, oa[1]);
  };

  auto BODY = [&](const bf16* kL, const bf16* vL) {
    asm volatile("s_waitcnt vmcnt(4)" ::: "memory");
    __builtin_amdgcn_s_barrier();              // tile visible to both waves
    asm volatile("" ::: "memory");
    TILE(kL, vL, qfA, oaA, lA);
    TILE(kL, vL, qfB, oaB, lB);
    asm volatile("" ::: "memory");
    __builtin_amdgcn_s_barrier();              // buffer consumed
    asm volatile("" ::: "memory");
  };

  // prologue: stage tiles 0 and 1 -> 8 outstanding gld16 per wave
  STAGE(&stage[0][0], p0);
  STAGE(&stage[1][0], p1);
  asm volatile("" ::: "memory");

  #pragma unroll 1
  for (int u = 0; u < 8; ++u) {
    BODY(kL0, vL0);
    p0 += adv;
    STAGE(&stage[0][0], p0);                   // tile 2u+2 (tail: OOB-unused)
    asm volatile("" ::: "memory");
    BODY(kL1, vL1);
    p1 += adv;
    STAGE(&stage[1][0], p1);                   // tile 2u+3 (tail: OOB-unused)
    asm volatile("" ::: "memory");
  }

  asm volatile("s_waitcnt vmcnt(0)" ::: "memory");

  // epilogue: write both tiles' unnormalized partials + l totals
  int tile0 = qb * 4 + wv * 2;
  #pragma unroll
  for (int s = 0; s < 2; s++) {
    f32x16* oa = s ? oaB : oaA;
    float l = s ? lB : lA;
    float ltot;
    {
      unsigned x = __builtin_bit_cast(unsigned, l), y = x;
      plane32swap(x, y);
      ltot = __builtin_bit_cast(float, x) + __builtin_bit_cast(float, y);
    }
    unsigned* op = Opart + (((size_t)(FQ * 8 + bh) * 128 + tile0 + s) * 1024);
    #pragma unroll
    for (int db = 0; db < 2; db++)
      #pragma unroll
      for (int j = 0; j < 8; j++) {
        int r = 2 * j;
        int d = db * 32 + 2 * (j & 1) + 8 * (j >> 1) + 4 * h32;
        op[(d >> 1) * 32 + lq] = pack2(oa[db][r], oa[db][r + 1]);
      }
    if (h32 == 0)
      Lp[((size_t)FQ * 8 + bh) * 4096 + (tile0 + s) * 32 + lq] = ltot;
  }
}

// ---------------------------------------------------------------------------
// Combine the 8 FQ partials (pure sums) -> AO[b][t][h*64+d] (bf16).
// grid = 1024 (8 bh x 128 tiles); bh = bid&7 keeps reads XCD-local.
// ---------------------------------------------------------------------------
__global__ __launch_bounds__(256)
void merge_kernel(const unsigned* __restrict__ Op, const float* __restrict__ Lp,
                  bf16* __restrict__ AO)
{
  int bid = blockIdx.x;
  int bh = bid & 7;
  int tile = bid >> 3;             // 0..127 (32-row tiles)
  int tid = threadIdx.x;
  int q = tid & 31;
  int c4 = tid >> 5;               // 0..7
  int row0 = tile * 32;

  float L = 0.f;
  #pragma unroll
  for (int p = 0; p < 8; p++)
    L += Lp[((size_t)p * 8 + bh) * 4096 + row0 + q];
  float inv = 1.f / L;

  __shared__ unsigned tl[32][33];
  float a0[4] = {}, a1[4] = {};
  #pragma unroll
  for (int p = 0; p < 8; p++) {
    const unsigned* src = Op + (((size_t)p * 8 + bh) * 128 + tile) * 1024;
    #pragma unroll
    for (int j = 0; j < 4; j++) {
      unsigned v = src[(c4 + j * 8) * 32 + q];
      a0[j] += (float)__builtin_bit_cast(bf16, (unsigned short)(v & 0xffff));
      a1[j] += (float)__builtin_bit_cast(bf16, (unsigned short)(v >> 16));
    }
  }
  #pragma unroll
  for (int j = 0; j < 4; j++)
    tl[q][c4 + j * 8] = pack2(a0[j] * inv, a1[j] * inv);
  __syncthreads();

  int q2 = tid >> 3;               // 0..31
  int dg = tid & 7;                // 0..7
  unsigned ov[4];
  #pragma unroll
  for (int i = 0; i < 4; i++) ov[i] = tl[q2][dg * 4 + i];
  int b_ = bh >> 2, hh = bh & 3;
  int row = row0 + q2;
  unsigned* dst = (unsigned*)(AO + ((size_t)b_ * 4096 + row) * 256 + hh * 64) + dg * 4;
  *reinterpret_cast<uint4*>(dst) = *reinterpret_cast<const uint4*>(ov);
}

// ---------------------------------------------------------------------------
extern "C" void kernel_launch(void* const* d_in, const int* in_sizes, int n_in,
                              void* d_out, int out_size, void* d_ws, size_t ws_size,
                              hipStream_t stream) {
  const float* t   = (const float*)d_in[0];
  const float* f   = (const float*)d_in[1];
  const float* nw  = (const float*)d_in[2];
  const float* wq  = (const float*)d_in[3];
  const float* bq  = (const float*)d_in[4];
  const float* wkv = (const float*)d_in[5];
  const float* bkv = (const float*)d_in[6];
  const float* wp  = (const float*)d_in[7];
  const float* bp  = (const float*)d_in[8];
  float* out = (float*)d_out;

  bf16* ws = (bf16*)d_ws;
  const size_t NTOK = 2097152;        // 2*4096*256 elements (4 MB bf16)
  bf16* tn   = ws;
  bf16* fn   = ws + NTOK;             // freed after gemm_qkv; reused as ao
  bf16* q    = ws + 2 * NTOK;
  bf16* k    = ws + 3 * NTOK;
  bf16* vt   = ws + 4 * NTOK;
  bf16* ao   = fn;                    // alias (merge writes after gemm_qkv)
  bf16* wqT  = ws + 5 * NTOK;
  bf16* wkvT = wqT + 65536;
  bf16* wpT  = wkvT + 131072;
  unsigned* opart = (unsigned*)(wpT + 65536);   // 8*8*128*1024 u32 = 33.6 MB
  float* lp = (float*)(opart + (size_t)8 * 8 * 128 * 1024);   // 1 MB

  prep_kernel<<<5120, 256, 0, stream>>>(t, f, nw, wq, wkv, wp, tn, fn, wqT, wkvT, wpT);
  gemm_qkv<<<1536, 256, 0, stream>>>(tn, fn, wqT, wkvT, bq, bkv, q, k, vt);
  attn_kernel<<<2048, 128, 0, stream>>>(q, k, vt, opart, lp);
  merge_kernel<<<1024, 256, 0, stream>>>(opart, lp, ao);
  gemm_out<<<512, 256, 0, stream>>>(ao, wpT, bp, tn, out);
}

// Round 16
// 95.706 us; speedup vs baseline: 1.1573x; 1.1573x over previous
//
#include <hip/hip_runtime.h>

typedef __bf16 bf16;
typedef __bf16 bf16x4 __attribute__((ext_vector_type(4)));
typedef __bf16 bf16x8 __attribute__((ext_vector_type(8)));
typedef float f32x2 __attribute__((ext_vector_type(2)));
typedef float f32x4 __attribute__((ext_vector_type(4)));
typedef float f32x16 __attribute__((ext_vector_type(16)));

__device__ __forceinline__ f32x4 mfma16(bf16x8 a, bf16x8 b, f32x4 c) {
  return __builtin_amdgcn_mfma_f32_16x16x32_bf16(a, b, c, 0, 0, 0);
}
__device__ __forceinline__ f32x16 mfma32(bf16x8 a, bf16x8 b, f32x16 c) {
  return __builtin_amdgcn_mfma_f32_32x32x16_bf16(a, b, c, 0, 0, 0);
}

__device__ __forceinline__ unsigned pack2(float lo, float hi) {
  unsigned short a = __builtin_bit_cast(unsigned short, (bf16)lo);
  unsigned short b = __builtin_bit_cast(unsigned short, (bf16)hi);
  return ((unsigned)b << 16) | (unsigned)a;
}

// single-instruction packed f32->2xbf16 (T12 recipe; HW-verified in R15)
__device__ __forceinline__ unsigned cvtpk(float lo, float hi) {
  unsigned r;
  asm("v_cvt_pk_bf16_f32 %0, %1, %2" : "=v"(r) : "v"(lo), "v"(hi));
  return r;
}

// v_permlane32_swap_b32 a, b:  a' = {a.lo, b.lo}, b' = {a.hi, b.hi}
__device__ __forceinline__ void plane32swap(unsigned& a, unsigned& b) {
  asm volatile("v_permlane32_swap_b32 %0, %1" : "+v"(a), "+v"(b));
}

// packed f32 add: 2 floats per instruction (CDNA VOP3P)
__device__ __forceinline__ f32x2 pk_add(f32x2 a, f32x2 b) {
  f32x2 d;
  asm("v_pk_add_f32 %0, %1, %2" : "=v"(d) : "v"(a), "v"(b));
  return d;
}

typedef __attribute__((address_space(3))) unsigned int lds_u32;
typedef __attribute__((address_space(1))) unsigned int glb_u32;
// async global->LDS, 16B per lane; LDS dest = base + lane*16 (wave-linear)
__device__ __forceinline__ void gld16(const bf16* g, bf16* l) {
  __builtin_amdgcn_global_load_lds((const glb_u32*)g, (lds_u32*)l, 16, 0, 0);
}

// ---------------------------------------------------------------------------
// prep: fused weight transposes (blocks 0..1023) + RMSNorm (blocks 1024..5119)
// ---------------------------------------------------------------------------
__global__ __launch_bounds__(256)
void prep_kernel(const float* __restrict__ t, const float* __restrict__ f,
                 const float* __restrict__ nw,
                 const float* __restrict__ wq, const float* __restrict__ wkv,
                 const float* __restrict__ wp,
                 bf16* __restrict__ tn, bf16* __restrict__ fn,
                 bf16* __restrict__ wqT, bf16* __restrict__ wkvT,
                 bf16* __restrict__ wpT)
{
  int b = blockIdx.x;
  if (b < 1024) {
    int e = b * 256 + threadIdx.x;   // 0..262143
    const float* src; bf16* dst; int N; int idx;
    if (e < 65536)       { src = wq;  dst = wqT;  N = 256; idx = e; }
    else if (e < 196608) { src = wkv; dst = wkvT; N = 512; idx = e - 65536; }
    else                 { src = wp;  dst = wpT;  N = 256; idx = e - 196608; }
    int k = idx & 255;
    int n = idx >> 8;
    dst[idx] = (bf16)src[(size_t)k * N + n];
    return;
  }
  int wave = threadIdx.x >> 6;
  int lane = threadIdx.x & 63;
  int row = (b - 1024) * 4 + wave;           // 0..16383
  const float* src;
  bf16* dst;
  if (row < 8192) {
    src = t + (size_t)row * 256;
    dst = tn + (size_t)row * 256;
  } else {
    int r2 = row - 8192;
    src = f + (size_t)r2 * 256;
    dst = fn + (size_t)r2 * 256;
  }
  float4 v = reinterpret_cast<const float4*>(src)[lane];
  float ss = v.x * v.x + v.y * v.y + v.z * v.z + v.w * v.w;
  #pragma unroll
  for (int m = 1; m < 64; m <<= 1) ss += __shfl_xor(ss, m);
  float nrm = rsqrtf(ss * (1.0f / 256.0f) + 1e-5f);
  float4 wv = reinterpret_cast<const float4*>(nw)[lane];
  bf16x4 o;
  o[0] = (bf16)(v.x * nrm * wv.x);
  o[1] = (bf16)(v.y * nrm * wv.y);
  o[2] = (bf16)(v.z * nrm * wv.z);
  o[3] = (bf16)(v.w * nrm * wv.w);
  *reinterpret_cast<bf16x4*>(dst + lane * 4) = o;
}

// ---------------------------------------------------------------------------
// LDS-staged GEMM body: out[M=8192, N] = A[8192,256](bf16) @ W[256,N] + bias
// ---------------------------------------------------------------------------
template<int MODE>
__device__ __forceinline__
void gemm_body(int bid, bf16 (*As)[264], bf16 (*Bs)[264],
               const bf16* __restrict__ A, const bf16* __restrict__ Wt,
               const float* __restrict__ bias, bf16* __restrict__ o0,
               bf16* __restrict__ o1, const bf16* __restrict__ resid,
               float* __restrict__ outf, int N)
{
  int tid = threadIdx.x;
  int wv = tid >> 6;
  int lane = tid & 63;
  int lr = lane & 15;
  int lk = (lane >> 4) * 8;
  int wm = wv >> 1, wn = wv & 1;
  int nb = N >> 6;
  int bm = bid / nb;
  int bn = bid - bm * nb;
  int row0 = bm * 64;
  int col0 = bn * 64;

  #pragma unroll
  for (int j = 0; j < 8; j++) {
    int idx = tid + 256 * j;            // 0..2047
    int r = idx >> 5, ch = idx & 31;    // row, 16B chunk
    *reinterpret_cast<bf16x8*>(&As[r][ch * 8]) =
        *reinterpret_cast<const bf16x8*>(A + (size_t)(row0 + r) * 256 + ch * 8);
    *reinterpret_cast<bf16x8*>(&Bs[r][ch * 8]) =
        *reinterpret_cast<const bf16x8*>(Wt + (size_t)(col0 + r) * 256 + ch * 8);
  }
  __syncthreads();

  f32x4 acc[2][2] = {};
  #pragma unroll
  for (int k0 = 0; k0 < 256; k0 += 32) {
    bf16x8 a[2], b[2];
    #pragma unroll
    for (int mi = 0; mi < 2; mi++)
      a[mi] = *reinterpret_cast<const bf16x8*>(&As[wm * 32 + mi * 16 + lr][k0 + lk]);
    #pragma unroll
    for (int ni = 0; ni < 2; ni++)
      b[ni] = *reinterpret_cast<const bf16x8*>(&Bs[wn * 32 + ni * 16 + lr][k0 + lk]);
    #pragma unroll
    for (int mi = 0; mi < 2; mi++)
      #pragma unroll
      for (int ni = 0; ni < 2; ni++)
        acc[mi][ni] = mfma16(a[mi], b[ni], acc[mi][ni]);
  }

  int rb = (lane >> 4) * 4;
  int row0w = row0 + wm * 32;
  int col0w = col0 + wn * 32;
  #pragma unroll
  for (int mi = 0; mi < 2; mi++) {
    #pragma unroll
    for (int ni = 0; ni < 2; ni++) {
      int col = col0w + ni * 16 + lr;
      float bv = bias[col];
      #pragma unroll
      for (int r = 0; r < 4; r++) {
        int row = row0w + mi * 16 + rb + r;
        float val = acc[mi][ni][r] + bv;
        if (MODE == 0) {
          int b_ = row >> 12, tt = row & 4095;
          int h = col >> 6, d = col & 63;
          o0[(((size_t)(b_ * 4 + h)) * 4096 + tt) * 64 + d] = (bf16)val;
        } else if (MODE == 1) {
          int b_ = row >> 12, ff = row & 4095;
          if (col < 256) {
            int h = col >> 6, d = col & 63;
            o0[(((size_t)(b_ * 4 + h)) * 4096 + ff) * 64 + d] = (bf16)val;
          } else {
            int c = col - 256;
            int h = c >> 6, d = c & 63;
            o1[(((size_t)(b_ * 4 + h)) * 64 + d) * 4096 + ff] = (bf16)val;
          }
        } else {
          size_t idx = (size_t)row * 256 + col;
          outf[idx] = val + (float)resid[idx];
        }
      }
    }
  }
}

// Fused Q-proj + KV-proj: blocks [0,512) do Q, [512,1536) do KV.
__global__ __launch_bounds__(256)
void gemm_qkv(const bf16* __restrict__ tn, const bf16* __restrict__ fn,
              const bf16* __restrict__ wqT, const bf16* __restrict__ wkvT,
              const float* __restrict__ bq, const float* __restrict__ bkv,
              bf16* __restrict__ q, bf16* __restrict__ k, bf16* __restrict__ vt)
{
  __shared__ bf16 As[64][264];
  __shared__ bf16 Bs[64][264];
  if (blockIdx.x < 512)
    gemm_body<0>(blockIdx.x, As, Bs, tn, wqT, bq, q, nullptr, nullptr, nullptr, 256);
  else
    gemm_body<1>(blockIdx.x - 512, As, Bs, fn, wkvT, bkv, k, vt, nullptr, nullptr, 512);
}

// Output projection + bias + residual.
__global__ __launch_bounds__(256)
void gemm_out(const bf16* __restrict__ ao, const bf16* __restrict__ wpT,
              const float* __restrict__ bp, const bf16* __restrict__ resid,
              float* __restrict__ outf)
{
  __shared__ bf16 As[64][264];
  __shared__ bf16 Bs[64][264];
  gemm_body<2>(blockIdx.x, As, Bs, ao, wpT, bp, nullptr, nullptr, resid, outf, 256);
}

// ---------------------------------------------------------------------------
// Flash attention v13 = v11 (R14, best measured) + cvt_pk P-pack + packed-l.
// 4 waves share ONE K/V stream; FQ=8 for 32 waves/CU supply.
// grid = 2048: bh = bid&7 (XCD affinity), qb = (bid>>3)&31 (128 q rows),
// FQ = bid>>8 (f-eighth, 512 f each, 16 iters of 32f).
// Block: 256 threads = 4 waves, wave w owns q-tile w (32 rows); all share
// the staged K/V tile. Staging roles {K-lo, K-hi, V-lo, V-hi}, 2 gld16
// each; counted vmcnt(2), raw-barrier double-buffer, VALU-diet body
// (zmm seed, x2 unroll, pointer-increment staging, benign tail overrun).
// Fixed-M softmax (bounded scores); pure-sum partials.
// ---------------------------------------------------------------------------
__global__ __launch_bounds__(256, 4)
void attn_kernel(const bf16* __restrict__ Q, const bf16* __restrict__ K,
                 const bf16* __restrict__ Vt, unsigned* __restrict__ Opart,
                 float* __restrict__ Lp)
{
  int bid = blockIdx.x;
  int bh = bid & 7;
  int qb = (bid >> 3) & 31;
  int FQ = bid >> 8;               // 0..7
  int wv = threadIdx.x >> 6;       // 0..3  (q-tile / staging role)
  int lane = threadIdx.x & 63;
  int lq = lane & 31;
  int h32 = lane >> 5;

  const bf16* Qb = Q + ((size_t)bh * 4096 + qb * 128 + wv * 32) * 64;
  const bf16* Kb = K + (size_t)bh * 4096 * 64;
  const bf16* Vb = Vt + (size_t)bh * 64 * 4096;

  __shared__ bf16 stage[2][4096];  // [buf][ K' 2048 | V' 2048 ]  16 KB

  const float qs = 0.125f * 1.44269504089f;
  bf16x8 qf[4];
  #pragma unroll
  for (int kc = 0; kc < 4; kc++) {
    qf[kc] = *reinterpret_cast<const bf16x8*>(Qb + (size_t)lq * 64 + kc * 16 + h32 * 8);
    #pragma unroll
    for (int i = 0; i < 8; i++) qf[kc][i] = (bf16)((float)qf[kc][i] * qs);
  }

  f32x16 zmm = {};                 // loop-invariant zero seed
  f32x16 oa[2] = {};
  f32x2 l2 = {0.f, 0.f};

  int fbeg = FQ * 512;

  // staging role: wv 0/1 = K chunk-pairs {0,1}/{2,3}; wv 2/3 = V {0,1}/{2,3}
  int role = wv >> 1;              // 0=K, 1=V
  int half = wv & 1;
  const bf16 *p0, *p1;
  if (role == 0) {
    p0 = Kb + (size_t)(fbeg + lq) * 64 + h32 * 8 + half * 32;
    p1 = p0 + 32 * 64;
  } else {
    p0 = Vb + (size_t)lane * 4096 + fbeg + half * 16;
    p1 = p0 + 32;
  }
  const int so  = role ? 8 : 16;         // source offset chunk->chunk+1
  const int adv = role ? 64 : 64 * 64;   // 2-tile source stride
  const int db0 = wv * 1024;             // LDS dest base for this wave's role

  // loop-invariant per-lane LDS read bases
  const bf16* kL0 = &stage[0][0] + h32 * 256 + lq * 8;
  const bf16* kL1 = &stage[1][0] + h32 * 256 + lq * 8;
  const bf16* vL0 = &stage[0][2048] + h32 * 512 + lq * 8;
  const bf16* vL1 = &stage[1][2048] + h32 * 512 + lq * 8;

  auto STAGE = [&](bf16* sb, const bf16* p) {
    gld16(p,      sb + db0);
    gld16(p + so, sb + db0 + 512);
  };

  auto BODY = [&](const bf16* kL, const bf16* vL) {
    asm volatile("s_waitcnt vmcnt(2)" ::: "memory");
    __builtin_amdgcn_s_barrier();              // tile visible to all 4 waves
    asm volatile("" ::: "memory");

    // S^T = K . Q^T (log2 units), seeded from hoisted zero
    f32x16 st = mfma32(*reinterpret_cast<const bf16x8*>(kL),        qf[0], zmm);
    st        = mfma32(*reinterpret_cast<const bf16x8*>(kL + 512),  qf[1], st);
    st        = mfma32(*reinterpret_cast<const bf16x8*>(kL + 1024), qf[2], st);
    st        = mfma32(*reinterpret_cast<const bf16x8*>(kL + 1536), qf[3], st);

    // fixed-M: p = exp2(st)
    union { f32x2 p2[8]; float s[16]; } u;
    #pragma unroll
    for (int r = 0; r < 16; r++) u.s[r] = exp2f(st[r]);

    // per-half l sum (packed accumulator; lane halves merged at epilogue)
    f32x2 a0 = pk_add(u.p2[0], u.p2[1]);
    f32x2 a1 = pk_add(u.p2[2], u.p2[3]);
    f32x2 a2 = pk_add(u.p2[4], u.p2[5]);
    f32x2 a3 = pk_add(u.p2[6], u.p2[7]);
    a0 = pk_add(a0, a1);
    a2 = pk_add(a2, a3);
    a0 = pk_add(a0, a2);
    l2 = pk_add(l2, a0);

    // P^T -> B-fragments: single-instr cvt_pk then permlane32_swap pairs
    unsigned w[8];
    #pragma unroll
    for (int j = 0; j < 8; j++) w[j] = cvtpk(u.s[2 * j], u.s[2 * j + 1]);
    plane32swap(w[0], w[2]);
    plane32swap(w[1], w[3]);
    plane32swap(w[4], w[6]);
    plane32swap(w[5], w[7]);
    union { unsigned u4[4]; bf16x8 v; } ub0, ub1;
    ub0.u4[0] = w[0]; ub0.u4[1] = w[1]; ub0.u4[2] = w[2]; ub0.u4[3] = w[3];
    ub1.u4[0] = w[4]; ub1.u4[1] = w[5]; ub1.u4[2] = w[6]; ub1.u4[3] = w[7];

    // O^T += Vt . P^T
    oa[0] = mfma32(*reinterpret_cast<const bf16x8*>(vL),        ub0.v, oa[0]);
    oa[0] = mfma32(*reinterpret_cast<const bf16x8*>(vL + 1024), ub1.v, oa[0]);
    oa[1] = mfma32(*reinterpret_cast<const bf16x8*>(vL + 256),  ub0.v, oa[1]);
    oa[1] = mfma32(*reinterpret_cast<const bf16x8*>(vL + 1280), ub1.v, oa[1]);

    asm volatile("" ::: "memory");
    __builtin_amdgcn_s_barrier();              // buffer consumed
    asm volatile("" ::: "memory");
  };

  // prologue: stage tiles 0 and 1 -> 4 outstanding gld16 per wave
  STAGE(&stage[0][0], p0);
  STAGE(&stage[1][0], p1);
  asm volatile("" ::: "memory");

  #pragma unroll 1
  for (int u = 0; u < 8; ++u) {
    BODY(kL0, vL0);
    p0 += adv;
    STAGE(&stage[0][0], p0);                   // tile 2u+2 (tail: OOB-unused)
    asm volatile("" ::: "memory");
    BODY(kL1, vL1);
    p1 += adv;
    STAGE(&stage[1][0], p1);                   // tile 2u+3 (tail: OOB-unused)
    asm volatile("" ::: "memory");
  }

  asm volatile("s_waitcnt vmcnt(0)" ::: "memory");

  // l: combine packed halves, then lane halves (both get the total)
  float l = l2[0] + l2[1];
  float ltot;
  {
    unsigned x = __builtin_bit_cast(unsigned, l), y = x;
    plane32swap(x, y);
    ltot = __builtin_bit_cast(float, x) + __builtin_bit_cast(float, y);
  }

  // write unnormalized partial O (packed bf16 pairs, [dp 32][q 32]) + l
  int tile = qb * 4 + wv;          // 0..127
  unsigned* op = Opart + (((size_t)(FQ * 8 + bh) * 128 + tile) * 1024);
  #pragma unroll
  for (int db = 0; db < 2; db++)
    #pragma unroll
    for (int j = 0; j < 8; j++) {
      int r = 2 * j;
      int d = db * 32 + 2 * (j & 1) + 8 * (j >> 1) + 4 * h32;
      op[(d >> 1) * 32 + lq] = pack2(oa[db][r], oa[db][r + 1]);
    }
  if (h32 == 0)
    Lp[((size_t)FQ * 8 + bh) * 4096 + tile * 32 + lq] = ltot;
}

// ---------------------------------------------------------------------------
// Combine the 8 FQ partials (pure sums) -> AO[b][t][h*64+d] (bf16).
// grid = 1024 (8 bh x 128 tiles); bh = bid&7 keeps reads XCD-local.
// ---------------------------------------------------------------------------
__global__ __launch_bounds__(256)
void merge_kernel(const unsigned* __restrict__ Op, const float* __restrict__ Lp,
                  bf16* __restrict__ AO)
{
  int bid = blockIdx.x;
  int bh = bid & 7;
  int tile = bid >> 3;             // 0..127 (32-row tiles)
  int tid = threadIdx.x;
  int q = tid & 31;
  int c4 = tid >> 5;               // 0..7
  int row0 = tile * 32;

  float L = 0.f;
  #pragma unroll
  for (int p = 0; p < 8; p++)
    L += Lp[((size_t)p * 8 + bh) * 4096 + row0 + q];
  float inv = 1.f / L;

  __shared__ unsigned tl[32][33];
  float a0[4] = {}, a1[4] = {};
  #pragma unroll
  for (int p = 0; p < 8; p++) {
    const unsigned* src = Op + (((size_t)p * 8 + bh) * 128 + tile) * 1024;
    #pragma unroll
    for (int j = 0; j < 4; j++) {
      unsigned v = src[(c4 + j * 8) * 32 + q];
      a0[j] += (float)__builtin_bit_cast(bf16, (unsigned short)(v & 0xffff));
      a1[j] += (float)__builtin_bit_cast(bf16, (unsigned short)(v >> 16));
    }
  }
  #pragma unroll
  for (int j = 0; j < 4; j++)
    tl[q][c4 + j * 8] = pack2(a0[j] * inv, a1[j] * inv);
  __syncthreads();

  int q2 = tid >> 3;               // 0..31
  int dg = tid & 7;                // 0..7
  unsigned ov[4];
  #pragma unroll
  for (int i = 0; i < 4; i++) ov[i] = tl[q2][dg * 4 + i];
  int b_ = bh >> 2, hh = bh & 3;
  int row = row0 + q2;
  unsigned* dst = (unsigned*)(AO + ((size_t)b_ * 4096 + row) * 256 + hh * 64) + dg * 4;
  *reinterpret_cast<uint4*>(dst) = *reinterpret_cast<const uint4*>(ov);
}

// ---------------------------------------------------------------------------
extern "C" void kernel_launch(void* const* d_in, const int* in_sizes, int n_in,
                              void* d_out, int out_size, void* d_ws, size_t ws_size,
                              hipStream_t stream) {
  const float* t   = (const float*)d_in[0];
  const float* f   = (const float*)d_in[1];
  const float* nw  = (const float*)d_in[2];
  const float* wq  = (const float*)d_in[3];
  const float* bq  = (const float*)d_in[4];
  const float* wkv = (const float*)d_in[5];
  const float* bkv = (const float*)d_in[6];
  const float* wp  = (const float*)d_in[7];
  const float* bp  = (const float*)d_in[8];
  float* out = (float*)d_out;

  bf16* ws = (bf16*)d_ws;
  const size_t NTOK = 2097152;        // 2*4096*256 elements (4 MB bf16)
  bf16* tn   = ws;
  bf16* fn   = ws + NTOK;             // freed after gemm_qkv; reused as ao
  bf16* q    = ws + 2 * NTOK;
  bf16* k    = ws + 3 * NTOK;
  bf16* vt   = ws + 4 * NTOK;
  bf16* ao   = fn;                    // alias (merge writes after gemm_qkv)
  bf16* wqT  = ws + 5 * NTOK;
  bf16* wkvT = wqT + 65536;
  bf16* wpT  = wkvT + 131072;
  unsigned* opart = (unsigned*)(wpT + 65536);   // 8*8*128*1024 u32 = 33.6 MB
  float* lp = (float*)(opart + (size_t)8 * 8 * 128 * 1024);   // 1 MB

  prep_kernel<<<5120, 256, 0, stream>>>(t, f, nw, wq, wkv, wp, tn, fn, wqT, wkvT, wpT);
  gemm_qkv<<<1536, 256, 0, stream>>>(tn, fn, wqT, wkvT, bq, bkv, q, k, vt);
  attn_kernel<<<2048, 256, 0, stream>>>(q, k, vt, opart, lp);
  merge_kernel<<<1024, 256, 0, stream>>>(opart, lp, ao);
  gemm_out<<<512, 256, 0, stream>>>(ao, wpT, bp, tn, out);
}

// Round 17
// 95.218 us; speedup vs baseline: 1.1633x; 1.0051x over previous
//
#include <hip/hip_runtime.h>

typedef __bf16 bf16;
typedef __bf16 bf16x4 __attribute__((ext_vector_type(4)));
typedef __bf16 bf16x8 __attribute__((ext_vector_type(8)));
typedef float f32x2 __attribute__((ext_vector_type(2)));
typedef float f32x4 __attribute__((ext_vector_type(4)));
typedef float f32x16 __attribute__((ext_vector_type(16)));

__device__ __forceinline__ f32x4 mfma16(bf16x8 a, bf16x8 b, f32x4 c) {
  return __builtin_amdgcn_mfma_f32_16x16x32_bf16(a, b, c, 0, 0, 0);
}
__device__ __forceinline__ f32x16 mfma32(bf16x8 a, bf16x8 b, f32x16 c) {
  return __builtin_amdgcn_mfma_f32_32x32x16_bf16(a, b, c, 0, 0, 0);
}

__device__ __forceinline__ unsigned pack2(float lo, float hi) {
  unsigned short a = __builtin_bit_cast(unsigned short, (bf16)lo);
  unsigned short b = __builtin_bit_cast(unsigned short, (bf16)hi);
  return ((unsigned)b << 16) | (unsigned)a;
}

// single-instruction packed f32->2xbf16 (T12 recipe; HW-verified in R15)
__device__ __forceinline__ unsigned cvtpk(float lo, float hi) {
  unsigned r;
  asm("v_cvt_pk_bf16_f32 %0, %1, %2" : "=v"(r) : "v"(lo), "v"(hi));
  return r;
}

// v_permlane32_swap_b32 a, b:  a' = {a.lo, b.lo}, b' = {a.hi, b.hi}
__device__ __forceinline__ void plane32swap(unsigned& a, unsigned& b) {
  asm volatile("v_permlane32_swap_b32 %0, %1" : "+v"(a), "+v"(b));
}

// packed f32 add: 2 floats per instruction (CDNA VOP3P)
__device__ __forceinline__ f32x2 pk_add(f32x2 a, f32x2 b) {
  f32x2 d;
  asm("v_pk_add_f32 %0, %1, %2" : "=v"(d) : "v"(a), "v"(b));
  return d;
}

typedef __attribute__((address_space(3))) unsigned int lds_u32;
typedef __attribute__((address_space(1))) unsigned int glb_u32;
// async global->LDS, 16B per lane; LDS dest = base + lane*16 (wave-linear)
__device__ __forceinline__ void gld16(const bf16* g, bf16* l) {
  __builtin_amdgcn_global_load_lds((const glb_u32*)g, (lds_u32*)l, 16, 0, 0);
}

// ---------------------------------------------------------------------------
// prep: fused weight transposes (blocks 0..1023) + RMSNorm (blocks 1024..5119)
// ---------------------------------------------------------------------------
__global__ __launch_bounds__(256)
void prep_kernel(const float* __restrict__ t, const float* __restrict__ f,
                 const float* __restrict__ nw,
                 const float* __restrict__ wq, const float* __restrict__ wkv,
                 const float* __restrict__ wp,
                 bf16* __restrict__ tn, bf16* __restrict__ fn,
                 bf16* __restrict__ wqT, bf16* __restrict__ wkvT,
                 bf16* __restrict__ wpT)
{
  int b = blockIdx.x;
  if (b < 1024) {
    int e = b * 256 + threadIdx.x;   // 0..262143
    const float* src; bf16* dst; int N; int idx;
    if (e < 65536)       { src = wq;  dst = wqT;  N = 256; idx = e; }
    else if (e < 196608) { src = wkv; dst = wkvT; N = 512; idx = e - 65536; }
    else                 { src = wp;  dst = wpT;  N = 256; idx = e - 196608; }
    int k = idx & 255;
    int n = idx >> 8;
    dst[idx] = (bf16)src[(size_t)k * N + n];
    return;
  }
  int wave = threadIdx.x >> 6;
  int lane = threadIdx.x & 63;
  int row = (b - 1024) * 4 + wave;           // 0..16383
  const float* src;
  bf16* dst;
  if (row < 8192) {
    src = t + (size_t)row * 256;
    dst = tn + (size_t)row * 256;
  } else {
    int r2 = row - 8192;
    src = f + (size_t)r2 * 256;
    dst = fn + (size_t)r2 * 256;
  }
  float4 v = reinterpret_cast<const float4*>(src)[lane];
  float ss = v.x * v.x + v.y * v.y + v.z * v.z + v.w * v.w;
  #pragma unroll
  for (int m = 1; m < 64; m <<= 1) ss += __shfl_xor(ss, m);
  float nrm = rsqrtf(ss * (1.0f / 256.0f) + 1e-5f);
  float4 wv = reinterpret_cast<const float4*>(nw)[lane];
  bf16x4 o;
  o[0] = (bf16)(v.x * nrm * wv.x);
  o[1] = (bf16)(v.y * nrm * wv.y);
  o[2] = (bf16)(v.z * nrm * wv.z);
  o[3] = (bf16)(v.w * nrm * wv.w);
  *reinterpret_cast<bf16x4*>(dst + lane * 4) = o;
}

// ---------------------------------------------------------------------------
// LDS-staged GEMM body: out[M=8192, N] = A[8192,256](bf16) @ W[256,N] + bias
// ---------------------------------------------------------------------------
template<int MODE>
__device__ __forceinline__
void gemm_body(int bid, bf16 (*As)[264], bf16 (*Bs)[264],
               const bf16* __restrict__ A, const bf16* __restrict__ Wt,
               const float* __restrict__ bias, bf16* __restrict__ o0,
               bf16* __restrict__ o1, const bf16* __restrict__ resid,
               float* __restrict__ outf, int N)
{
  int tid = threadIdx.x;
  int wv = tid >> 6;
  int lane = tid & 63;
  int lr = lane & 15;
  int lk = (lane >> 4) * 8;
  int wm = wv >> 1, wn = wv & 1;
  int nb = N >> 6;
  int bm = bid / nb;
  int bn = bid - bm * nb;
  int row0 = bm * 64;
  int col0 = bn * 64;

  #pragma unroll
  for (int j = 0; j < 8; j++) {
    int idx = tid + 256 * j;            // 0..2047
    int r = idx >> 5, ch = idx & 31;    // row, 16B chunk
    *reinterpret_cast<bf16x8*>(&As[r][ch * 8]) =
        *reinterpret_cast<const bf16x8*>(A + (size_t)(row0 + r) * 256 + ch * 8);
    *reinterpret_cast<bf16x8*>(&Bs[r][ch * 8]) =
        *reinterpret_cast<const bf16x8*>(Wt + (size_t)(col0 + r) * 256 + ch * 8);
  }
  __syncthreads();

  f32x4 acc[2][2] = {};
  #pragma unroll
  for (int k0 = 0; k0 < 256; k0 += 32) {
    bf16x8 a[2], b[2];
    #pragma unroll
    for (int mi = 0; mi < 2; mi++)
      a[mi] = *reinterpret_cast<const bf16x8*>(&As[wm * 32 + mi * 16 + lr][k0 + lk]);
    #pragma unroll
    for (int ni = 0; ni < 2; ni++)
      b[ni] = *reinterpret_cast<const bf16x8*>(&Bs[wn * 32 + ni * 16 + lr][k0 + lk]);
    #pragma unroll
    for (int mi = 0; mi < 2; mi++)
      #pragma unroll
      for (int ni = 0; ni < 2; ni++)
        acc[mi][ni] = mfma16(a[mi], b[ni], acc[mi][ni]);
  }

  int rb = (lane >> 4) * 4;
  int row0w = row0 + wm * 32;
  int col0w = col0 + wn * 32;
  #pragma unroll
  for (int mi = 0; mi < 2; mi++) {
    #pragma unroll
    for (int ni = 0; ni < 2; ni++) {
      int col = col0w + ni * 16 + lr;
      float bv = bias[col];
      #pragma unroll
      for (int r = 0; r < 4; r++) {
        int row = row0w + mi * 16 + rb + r;
        float val = acc[mi][ni][r] + bv;
        if (MODE == 0) {
          int b_ = row >> 12, tt = row & 4095;
          int h = col >> 6, d = col & 63;
          o0[(((size_t)(b_ * 4 + h)) * 4096 + tt) * 64 + d] = (bf16)val;
        } else if (MODE == 1) {
          int b_ = row >> 12, ff = row & 4095;
          if (col < 256) {
            int h = col >> 6, d = col & 63;
            o0[(((size_t)(b_ * 4 + h)) * 4096 + ff) * 64 + d] = (bf16)val;
          } else {
            int c = col - 256;
            int h = c >> 6, d = c & 63;
            o1[(((size_t)(b_ * 4 + h)) * 64 + d) * 4096 + ff] = (bf16)val;
          }
        } else {
          size_t idx = (size_t)row * 256 + col;
          outf[idx] = val + (float)resid[idx];
        }
      }
    }
  }
}

// Fused Q-proj + KV-proj: blocks [0,512) do Q, [512,1536) do KV.
__global__ __launch_bounds__(256)
void gemm_qkv(const bf16* __restrict__ tn, const bf16* __restrict__ fn,
              const bf16* __restrict__ wqT, const bf16* __restrict__ wkvT,
              const float* __restrict__ bq, const float* __restrict__ bkv,
              bf16* __restrict__ q, bf16* __restrict__ k, bf16* __restrict__ vt)
{
  __shared__ bf16 As[64][264];
  __shared__ bf16 Bs[64][264];
  if (blockIdx.x < 512)
    gemm_body<0>(blockIdx.x, As, Bs, tn, wqT, bq, q, nullptr, nullptr, nullptr, 256);
  else
    gemm_body<1>(blockIdx.x - 512, As, Bs, fn, wkvT, bkv, k, vt, nullptr, nullptr, 512);
}

// Output projection + bias + residual.
__global__ __launch_bounds__(256)
void gemm_out(const bf16* __restrict__ ao, const bf16* __restrict__ wpT,
              const float* __restrict__ bp, const bf16* __restrict__ resid,
              float* __restrict__ outf)
{
  __shared__ bf16 As[64][264];
  __shared__ bf16 Bs[64][264];
  gemm_body<2>(blockIdx.x, As, Bs, ao, wpT, bp, nullptr, nullptr, resid, outf, 256);
}

// ---------------------------------------------------------------------------
// Flash attention v14 = v13 + exp/PV interleave (dependency-chain split).
// The softmax->pack->PV string is split into two independent 8-score halves:
// PV MFMAs for half 0 (ub0) issue on the matrix pipe WHILE half 1's exp2s
// run on the VALU/trans pipe. Pure reorder — bit-identical math.
// 4 waves share ONE K/V stream; FQ=8 for wave supply.
// grid = 2048: bh = bid&7 (XCD affinity), qb = (bid>>3)&31 (128 q rows),
// FQ = bid>>8 (f-eighth, 512 f each, 16 iters of 32f).
// Staging roles {K-lo, K-hi, V-lo, V-hi}, 2 gld16 each; counted vmcnt(2),
// raw-barrier double-buffer, VALU-diet body. Fixed-M softmax; pure-sum
// partials.
// ---------------------------------------------------------------------------
__global__ __launch_bounds__(256, 4)
void attn_kernel(const bf16* __restrict__ Q, const bf16* __restrict__ K,
                 const bf16* __restrict__ Vt, unsigned* __restrict__ Opart,
                 float* __restrict__ Lp)
{
  int bid = blockIdx.x;
  int bh = bid & 7;
  int qb = (bid >> 3) & 31;
  int FQ = bid >> 8;               // 0..7
  int wv = threadIdx.x >> 6;       // 0..3  (q-tile / staging role)
  int lane = threadIdx.x & 63;
  int lq = lane & 31;
  int h32 = lane >> 5;

  const bf16* Qb = Q + ((size_t)bh * 4096 + qb * 128 + wv * 32) * 64;
  const bf16* Kb = K + (size_t)bh * 4096 * 64;
  const bf16* Vb = Vt + (size_t)bh * 64 * 4096;

  __shared__ bf16 stage[2][4096];  // [buf][ K' 2048 | V' 2048 ]  16 KB

  const float qs = 0.125f * 1.44269504089f;
  bf16x8 qf[4];
  #pragma unroll
  for (int kc = 0; kc < 4; kc++) {
    qf[kc] = *reinterpret_cast<const bf16x8*>(Qb + (size_t)lq * 64 + kc * 16 + h32 * 8);
    #pragma unroll
    for (int i = 0; i < 8; i++) qf[kc][i] = (bf16)((float)qf[kc][i] * qs);
  }

  f32x16 zmm = {};                 // loop-invariant zero seed
  f32x16 oa[2] = {};
  f32x2 l2 = {0.f, 0.f};

  int fbeg = FQ * 512;

  // staging role: wv 0/1 = K chunk-pairs {0,1}/{2,3}; wv 2/3 = V {0,1}/{2,3}
  int role = wv >> 1;              // 0=K, 1=V
  int half = wv & 1;
  const bf16 *p0, *p1;
  if (role == 0) {
    p0 = Kb + (size_t)(fbeg + lq) * 64 + h32 * 8 + half * 32;
    p1 = p0 + 32 * 64;
  } else {
    p0 = Vb + (size_t)lane * 4096 + fbeg + half * 16;
    p1 = p0 + 32;
  }
  const int so  = role ? 8 : 16;         // source offset chunk->chunk+1
  const int adv = role ? 64 : 64 * 64;   // 2-tile source stride
  const int db0 = wv * 1024;             // LDS dest base for this wave's role

  // loop-invariant per-lane LDS read bases
  const bf16* kL0 = &stage[0][0] + h32 * 256 + lq * 8;
  const bf16* kL1 = &stage[1][0] + h32 * 256 + lq * 8;
  const bf16* vL0 = &stage[0][2048] + h32 * 512 + lq * 8;
  const bf16* vL1 = &stage[1][2048] + h32 * 512 + lq * 8;

  auto STAGE = [&](bf16* sb, const bf16* p) {
    gld16(p,      sb + db0);
    gld16(p + so, sb + db0 + 512);
  };

  auto BODY = [&](const bf16* kL, const bf16* vL) {
    asm volatile("s_waitcnt vmcnt(2)" ::: "memory");
    __builtin_amdgcn_s_barrier();              // tile visible to all 4 waves
    asm volatile("" ::: "memory");

    // S^T = K . Q^T (log2 units), seeded from hoisted zero
    f32x16 st = mfma32(*reinterpret_cast<const bf16x8*>(kL),        qf[0], zmm);
    st        = mfma32(*reinterpret_cast<const bf16x8*>(kL + 512),  qf[1], st);
    st        = mfma32(*reinterpret_cast<const bf16x8*>(kL + 1024), qf[2], st);
    st        = mfma32(*reinterpret_cast<const bf16x8*>(kL + 1536), qf[3], st);

    // ---- half 0: f-slots 0..15 (s[0..7]) ----
    float s0[8];
    #pragma unroll
    for (int r = 0; r < 8; r++) s0[r] = exp2f(st[r]);
    unsigned w0 = cvtpk(s0[0], s0[1]);
    unsigned w1 = cvtpk(s0[2], s0[3]);
    unsigned w2 = cvtpk(s0[4], s0[5]);
    unsigned w3 = cvtpk(s0[6], s0[7]);
    plane32swap(w0, w2);
    plane32swap(w1, w3);
    union { unsigned u4[4]; bf16x8 v; } ub0;
    ub0.u4[0] = w0; ub0.u4[1] = w1; ub0.u4[2] = w2; ub0.u4[3] = w3;

    // PV with ub0 issues on the matrix pipe; half 1's exps overlap on VALU
    oa[0] = mfma32(*reinterpret_cast<const bf16x8*>(vL),       ub0.v, oa[0]);
    oa[1] = mfma32(*reinterpret_cast<const bf16x8*>(vL + 256), ub0.v, oa[1]);

    // ---- half 1: f-slots 16..31 (s[8..15]) ----
    float s1[8];
    #pragma unroll
    for (int r = 0; r < 8; r++) s1[r] = exp2f(st[8 + r]);
    unsigned w4 = cvtpk(s1[0], s1[1]);
    unsigned w5 = cvtpk(s1[2], s1[3]);
    unsigned w6 = cvtpk(s1[4], s1[5]);
    unsigned w7 = cvtpk(s1[6], s1[7]);
    plane32swap(w4, w6);
    plane32swap(w5, w7);
    union { unsigned u4[4]; bf16x8 v; } ub1;
    ub1.u4[0] = w4; ub1.u4[1] = w5; ub1.u4[2] = w6; ub1.u4[3] = w7;

    oa[0] = mfma32(*reinterpret_cast<const bf16x8*>(vL + 1024), ub1.v, oa[0]);
    oa[1] = mfma32(*reinterpret_cast<const bf16x8*>(vL + 1280), ub1.v, oa[1]);

    // l sums (both halves; overlaps PV latency)
    f32x2* q0 = reinterpret_cast<f32x2*>(s0);
    f32x2* q1 = reinterpret_cast<f32x2*>(s1);
    f32x2 a0 = pk_add(q0[0], q0[1]);
    f32x2 a1 = pk_add(q0[2], q0[3]);
    f32x2 a2 = pk_add(q1[0], q1[1]);
    f32x2 a3 = pk_add(q1[2], q1[3]);
    a0 = pk_add(a0, a1);
    a2 = pk_add(a2, a3);
    a0 = pk_add(a0, a2);
    l2 = pk_add(l2, a0);

    asm volatile("" ::: "memory");
    __builtin_amdgcn_s_barrier();              // buffer consumed
    asm volatile("" ::: "memory");
  };

  // prologue: stage tiles 0 and 1 -> 4 outstanding gld16 per wave
  STAGE(&stage[0][0], p0);
  STAGE(&stage[1][0], p1);
  asm volatile("" ::: "memory");

  #pragma unroll 1
  for (int u = 0; u < 8; ++u) {
    BODY(kL0, vL0);
    p0 += adv;
    STAGE(&stage[0][0], p0);                   // tile 2u+2 (tail: OOB-unused)
    asm volatile("" ::: "memory");
    BODY(kL1, vL1);
    p1 += adv;
    STAGE(&stage[1][0], p1);                   // tile 2u+3 (tail: OOB-unused)
    asm volatile("" ::: "memory");
  }

  asm volatile("s_waitcnt vmcnt(0)" ::: "memory");

  // l: combine packed halves, then lane halves (both get the total)
  float l = l2[0] + l2[1];
  float ltot;
  {
    unsigned x = __builtin_bit_cast(unsigned, l), y = x;
    plane32swap(x, y);
    ltot = __builtin_bit_cast(float, x) + __builtin_bit_cast(float, y);
  }

  // write unnormalized partial O (packed bf16 pairs, [dp 32][q 32]) + l
  int tile = qb * 4 + wv;          // 0..127
  unsigned* op = Opart + (((size_t)(FQ * 8 + bh) * 128 + tile) * 1024);
  #pragma unroll
  for (int db = 0; db < 2; db++)
    #pragma unroll
    for (int j = 0; j < 8; j++) {
      int r = 2 * j;
      int d = db * 32 + 2 * (j & 1) + 8 * (j >> 1) + 4 * h32;
      op[(d >> 1) * 32 + lq] = cvtpk(oa[db][r], oa[db][r + 1]);
    }
  if (h32 == 0)
    Lp[((size_t)FQ * 8 + bh) * 4096 + tile * 32 + lq] = ltot;
}

// ---------------------------------------------------------------------------
// Combine the 8 FQ partials (pure sums) -> AO[b][t][h*64+d] (bf16).
// grid = 1024 (8 bh x 128 tiles); bh = bid&7 keeps reads XCD-local.
// ---------------------------------------------------------------------------
__global__ __launch_bounds__(256)
void merge_kernel(const unsigned* __restrict__ Op, const float* __restrict__ Lp,
                  bf16* __restrict__ AO)
{
  int bid = blockIdx.x;
  int bh = bid & 7;
  int tile = bid >> 3;             // 0..127 (32-row tiles)
  int tid = threadIdx.x;
  int q = tid & 31;
  int c4 = tid >> 5;               // 0..7
  int row0 = tile * 32;

  float L = 0.f;
  #pragma unroll
  for (int p = 0; p < 8; p++)
    L += Lp[((size_t)p * 8 + bh) * 4096 + row0 + q];
  float inv = 1.f / L;

  __shared__ unsigned tl[32][33];
  float a0[4] = {}, a1[4] = {};
  #pragma unroll
  for (int p = 0; p < 8; p++) {
    const unsigned* src = Op + (((size_t)p * 8 + bh) * 128 + tile) * 1024;
    #pragma unroll
    for (int j = 0; j < 4; j++) {
      unsigned v = src[(c4 + j * 8) * 32 + q];
      a0[j] += (float)__builtin_bit_cast(bf16, (unsigned short)(v & 0xffff));
      a1[j] += (float)__builtin_bit_cast(bf16, (unsigned short)(v >> 16));
    }
  }
  #pragma unroll
  for (int j = 0; j < 4; j++)
    tl[q][c4 + j * 8] = pack2(a0[j] * inv, a1[j] * inv);
  __syncthreads();

  int q2 = tid >> 3;               // 0..31
  int dg = tid & 7;                // 0..7
  unsigned ov[4];
  #pragma unroll
  for (int i = 0; i < 4; i++) ov[i] = tl[q2][dg * 4 + i];
  int b_ = bh >> 2, hh = bh & 3;
  int row = row0 + q2;
  unsigned* dst = (unsigned*)(AO + ((size_t)b_ * 4096 + row) * 256 + hh * 64) + dg * 4;
  *reinterpret_cast<uint4*>(dst) = *reinterpret_cast<const uint4*>(ov);
}

// ---------------------------------------------------------------------------
extern "C" void kernel_launch(void* const* d_in, const int* in_sizes, int n_in,
                              void* d_out, int out_size, void* d_ws, size_t ws_size,
                              hipStream_t stream) {
  const float* t   = (const float*)d_in[0];
  const float* f   = (const float*)d_in[1];
  const float* nw  = (const float*)d_in[2];
  const float* wq  = (const float*)d_in[3];
  const float* bq  = (const float*)d_in[4];
  const float* wkv = (const float*)d_in[5];
  const float* bkv = (const float*)d_in[6];
  const float* wp  = (const float*)d_in[7];
  const float* bp  = (const float*)d_in[8];
  float* out = (float*)d_out;

  bf16* ws = (bf16*)d_ws;
  const size_t NTOK = 2097152;        // 2*4096*256 elements (4 MB bf16)
  bf16* tn   = ws;
  bf16* fn   = ws + NTOK;             // freed after gemm_qkv; reused as ao
  bf16* q    = ws + 2 * NTOK;
  bf16* k    = ws + 3 * NTOK;
  bf16* vt   = ws + 4 * NTOK;
  bf16* ao   = fn;                    // alias (merge writes after gemm_qkv)
  bf16* wqT  = ws + 5 * NTOK;
  bf16* wkvT = wqT + 65536;
  bf16* wpT  = wkvT + 131072;
  unsigned* opart = (unsigned*)(wpT + 65536);   // 8*8*128*1024 u32 = 33.6 MB
  float* lp = (float*)(opart + (size_t)8 * 8 * 128 * 1024);   // 1 MB

  prep_kernel<<<5120, 256, 0, stream>>>(t, f, nw, wq, wkv, wp, tn, fn, wqT, wkvT, wpT);
  gemm_qkv<<<1536, 256, 0, stream>>>(tn, fn, wqT, wkvT, bq, bkv, q, k, vt);
  attn_kernel<<<2048, 256, 0, stream>>>(q, k, vt, opart, lp);
  merge_kernel<<<1024, 256, 0, stream>>>(opart, lp, ao);
  gemm_out<<<512, 256, 0, stream>>>(ao, wpT, bp, tn, out);
}